// Round 4
// baseline (241.189 us; speedup 1.0000x reference)
//
#include <hip/hip_runtime.h>

#define NPOS 21824          // 16384+4096+1024+256+64 positions per image
#define MINS 0.05f
#define BT   1024           // threads per block for k_nms (16 waves)
#define NW   (BT/64)
#define TFAST 0.85f         // static pre-filter threshold (fast path only)
#define CAP  16384          // per-image compact-list capacity

struct Ptrs { const float* cls[5]; const float* reg[5]; const float* ctr[5]; };

__device__ __forceinline__ float sigf(float x){ return 1.0f/(1.0f+expf(-x)); }

// key = (score_bits<<16) | (65535-p): desc key == desc score, ties lower p.
// Matches reference ordering (concatenation order = level-major position p;
// argmax picks first max; jax top_k keeps lower index on ties).
__device__ __forceinline__ unsigned long long mkkey(unsigned int b, int p){
    return ((unsigned long long)b << 16) | (unsigned)(65535 - p);
}

// Recompute the snapped box for position p (bit-identical to the original
// k_score path: same expression order, same expf, same casts/clamps).
__device__ __forceinline__ float4 computeBox(const Ptrs& P, int img, int p){
    int base, lw, stride, lvl;
    if (p < 16384)      { lvl=0; base=0;     lw=7; stride=8;   }
    else if (p < 20480) { lvl=1; base=16384; lw=6; stride=16;  }
    else if (p < 21504) { lvl=2; base=20480; lw=5; stride=32;  }
    else if (p < 21760) { lvl=3; base=21504; lw=4; stride=64;  }
    else                { lvl=4; base=21760; lw=3; stride=128; }
    int pl = p - base;
    int h = pl >> lw, w = pl & ((1<<lw)-1);
    long long lidx = (long long)img*(1<<(2*lw)) + pl;
    float4 rg = ((const float4*)P.reg[lvl])[lidx];
    float x = (w + 0.5f)*(float)stride;
    float y = (h + 0.5f)*(float)stride;
    int ix1 = (int)(x - expf(rg.x));
    int iy1 = (int)(y - expf(rg.y));
    int ix2 = (int)(x + expf(rg.z));
    int iy2 = (int)(y + expf(rg.w));
    ix1 = max(ix1,0); iy1 = max(iy1,0);
    ix2 = min(ix2,1023); iy2 = min(iy2,1023);
    return make_float4((float)ix1,(float)iy1,(float)ix2,(float)iy2);
}

// ---------------- Kernel A: score / class + compact candidate list ---------
__global__ __launch_bounds__(256) void k_score(Ptrs P, float* scoreAll, int* clsAll,
                                               unsigned long long* list, int* listCnt)
{
    int img  = blockIdx.y;
    int blk  = blockIdx.x;           // [0,341)
    int tid  = threadIdx.x;
    int posb = tid >> 2;             // position within block [0,64)
    int l    = tid & 3;              // lane within 4-lane group
    int p    = blk*64 + posb;
    int lvl, base, lw;
    if (blk < 256)      { lvl=0; base=0;     lw=7; }
    else if (blk < 320) { lvl=1; base=16384; lw=6; }
    else if (blk < 336) { lvl=2; base=20480; lw=5; }
    else if (blk < 340) { lvl=3; base=21504; lw=4; }
    else                { lvl=4; base=21760; lw=3; }
    int pl = p - base;
    long long lidx = (long long)img*(1<<(2*lw)) + pl;

    const float4* c4 = (const float4*)(P.cls[lvl] + lidx*80);
    float mx = -3.4e38f; int mi = 0;
#pragma unroll
    for (int j = 0; j < 5; ++j) {
        int k = j*4 + l;
        float4 v = c4[k];
        int cb = k*4;
        if (v.x > mx){mx=v.x; mi=cb;}
        if (v.y > mx){mx=v.y; mi=cb+1;}
        if (v.z > mx){mx=v.z; mi=cb+2;}
        if (v.w > mx){mx=v.w; mi=cb+3;}
    }
#pragma unroll
    for (int d = 1; d < 4; d <<= 1) {
        float omx = __shfl_xor(mx, d);
        int   omi = __shfl_xor(mi, d);
        if (omx > mx || (omx == mx && omi < mi)) { mx = omx; mi = omi; }
    }
    if (l == 0) {
        float ct = P.ctr[lvl][lidx];
        float sc = sqrtf(sigf(mx)*sigf(ct));   // sigmoid(max)==max(sigmoid)
        int o = img*NPOS + p;
        scoreAll[o] = sc;
        clsAll[o]   = mi;
        if (sc > TFAST) {                      // compact-list append (fast path)
            int t = atomicAdd(&listCnt[img], 1);
            if (t < CAP) list[(long long)img*CAP + t] = mkkey(__float_as_uint(sc), p);
        }
    }
}

// ---- suffix-scan pick over a 2048-bin LDS histogram (2 bins/thread) --------
// Finds the bin where the descending cumulative count crosses K; writes
// shPref = prefBase | (bin<<shift), shK = K remaining within that bin.
__device__ void suffix_pick(const int* hist, int* wsum, int K,
                            unsigned int prefBase, int shift,
                            unsigned int* shPref, int* shK, int tid)
{
    int lo = tid*2;
    int h0 = hist[lo], h1 = hist[lo+1];
    int ls = h0 + h1;
    int lane = tid & 63, wv = tid >> 6;
    int v = ls;
#pragma unroll
    for (int off = 1; off < 64; off <<= 1) {
        int o = __shfl_down(v, off);
        if (lane + off < 64) v += o;
    }
    if (lane == 0) wsum[wv] = v;
    __syncthreads();
    int add = 0;
    for (int q = wv + 1; q < NW; ++q) add += wsum[q];
    int mine = v + add;              // count in bins [lo..2047]
    int above = mine - ls;           // count in bins [lo+2..2047]
    if (above < K && mine >= K) {    // exactly one thread crosses
        if (above + h1 >= K) { *shPref = prefBase | ((unsigned)(lo+1) << shift); *shK = K - above; }
        else                 { *shPref = prefBase | ((unsigned)lo << shift); *shK = K - above - h1; }
    }
    __syncthreads();
}

// ------ Kernel B: global top-256 + rank + matrix-NMS (8 blocks, 1024 thr) ---
// Fast path: radix-select over the compact list (all positions with
// score > TFAST). cnt>=256 guarantees the global top-256 is inside the list
// (256th score > TFAST); cnt<=CAP guarantees no append was dropped. Otherwise
// fall back to exact full-scan radix over scoreAll.
// Greedy NMS == sequential scan over rank order with a 256-bit suppression
// mask: candidate i accepted iff bit i clear; on accept, OR in row i of the
// precomputed (parallel-built) IoU>thr matrix. Identical decisions to serial
// greedy NMS.
__global__ __launch_bounds__(BT) void k_nms(Ptrs P, const float* scoreAll,
                                            const int* clsAll,
                                            const unsigned long long* list,
                                            const int* listCnt, float* out)
{
    __shared__ int histA[2048], histB[2048], wsum[NW];
    __shared__ unsigned int shPref;
    __shared__ int shK, tick, eqn;
    __shared__ unsigned long long eqKey[1024];
    __shared__ unsigned long long sel[256];
    __shared__ unsigned long long sorted[256];
    __shared__ float4 sBox[256];
    __shared__ float  sCls[256];
    __shared__ __align__(16) unsigned long long sRow[256][4];
    __shared__ int accIdx[100];
    __shared__ float4 accBox[100];
    __shared__ int shNaM, shNa;
    __shared__ unsigned long long shLast;

    int img = blockIdx.x, tid = threadIdx.x;
    const unsigned int* gs = (const unsigned int*)scoreAll + (long long)img*NPOS;
    const int* gCls = clsAll + (long long)img*NPOS;
    const unsigned long long* gl = list + (long long)img*CAP;

    float* outS = out + img*100;
    float* outC = out + 800 + img*100;
    float* outB = out + 1600 + img*400;

    int cnt = listCnt[img];
    bool fastPath = (cnt >= 256 && cnt <= CAP);

    for (int i = tid; i < 2048; i += BT) { histA[i] = 0; histB[i] = 0; }
    if (tid == 0) { tick = 0; eqn = 0; }
    __syncthreads();

    unsigned int kth; int need;
    if (fastPath) {
        // ---- radix over compact list (key>>35 = score_bits>>19) ----
        for (int i = tid; i < cnt; i += BT)
            atomicAdd(&histA[(unsigned)(gl[i] >> 35)], 1);
        __syncthreads();
        suffix_pick(histA, wsum, 256, 0u, 19, &shPref, &shK, tid);
        unsigned int pref = shPref; int K2 = shK;
        for (int i = tid; i < cnt; i += BT) {
            unsigned long long k = gl[i];
            if ((unsigned)(k >> 35) == (pref >> 19))
                atomicAdd(&histB[(unsigned)(k >> 24) & 2047], 1);
        }
        __syncthreads();
        suffix_pick(histB, wsum, K2, pref, 8, &shPref, &shK, tid);
        kth = shPref >> 8; need = shK;
        for (int i = tid; i < cnt; i += BT) {
            unsigned long long k = gl[i];
            unsigned int hb = (unsigned)(k >> 24);
            if (hb > kth)       { int t = atomicAdd(&tick, 1); sel[t] = k; }
            else if (hb == kth) { int t = atomicAdd(&eqn, 1); if (t < 1024) eqKey[t] = k; }
        }
    } else {
        // ---- exact full-scan radix over all positions ----
#pragma unroll 4
        for (int i = tid; i < NPOS; i += BT)
            atomicAdd(&histA[gs[i] >> 19], 1);
        __syncthreads();
        suffix_pick(histA, wsum, 256, 0u, 19, &shPref, &shK, tid);
        unsigned int pref = shPref; int K2 = shK;
#pragma unroll 4
        for (int i = tid; i < NPOS; i += BT) {
            unsigned int b = gs[i];
            if ((b >> 19) == (pref >> 19)) atomicAdd(&histB[(b >> 8) & 2047], 1);
        }
        __syncthreads();
        suffix_pick(histB, wsum, K2, pref, 8, &shPref, &shK, tid);
        kth = shPref >> 8; need = shK;
#pragma unroll 4
        for (int i = tid; i < NPOS; i += BT) {
            unsigned int b = gs[i], hb = b >> 8;
            if (hb > kth)       { int t = atomicAdd(&tick, 1); sel[t] = mkkey(b, i); }
            else if (hb == kth) { int t = atomicAdd(&eqn, 1); if (t < 1024) eqKey[t] = mkkey(b, i); }
        }
    }
    __syncthreads();
    int m = eqn, nG = tick;              // nG == 256-need
    if (m <= 1024) {                     // keep `need` LARGEST keys among ties
        for (int q = tid; q < m; q += BT) {
            unsigned long long kq = eqKey[q];
            int r = 0;
            for (int j = 0; j < m; ++j) r += (eqKey[j] > kq);
            if (r < need) sel[nG + r] = kq;
        }
    } else if (tid == 0) {               // unreachable-in-practice fallback
        unsigned long long last = ~0ULL;
        for (int c = 0; c < need; ++c) {
            unsigned long long best = 0;
            if (fastPath) {
                for (int i = 0; i < cnt; ++i) {
                    unsigned long long k2 = gl[i];
                    if ((unsigned)(k2 >> 24) == kth && k2 < last && k2 > best) best = k2;
                }
            } else {
                for (int i = 0; i < NPOS; ++i) {
                    unsigned int b = gs[i];
                    if ((b >> 8) == kth) {
                        unsigned long long k2 = mkkey(b, i);
                        if (k2 < last && k2 > best) best = k2;
                    }
                }
            }
            sel[nG + c] = best; last = best;
        }
    }
    __syncthreads();

    // rank 256 unique keys by counting (1 key/thread, broadcast LDS reads)
    if (tid < 256) {
        unsigned long long k = sel[tid];
        int r = 0;
        for (int j = 0; j < 256; ++j) r += (sel[j] > k);
        sorted[r] = k;
    }
    __syncthreads();
    if (tid < 256) {
        int p = 65535 - (int)(sorted[tid] & 0xFFFF);
        sBox[tid] = computeBox(P, img, p);
        sCls[tid] = (float)gCls[p];
    }

    // nValid = # leading candidates with score > MINS (sorted desc, so prefix).
    // __syncthreads_count doubles as the barrier covering sBox/sCls writes.
    float myScore = 0.f;
    if (tid < 256) myScore = __uint_as_float((unsigned int)(sorted[tid] >> 16));
    int nValid = __syncthreads_count(myScore > MINS ? 1 : 0);

    // ---- suppression matrix: thread (row,quarter) builds 64 bits of row ----
    // Float arithmetic order matches serial greedy NMS exactly:
    // den = area(candidate j) + area(accepted i) - inter + 1e-12.
    {
        int row = tid & 255, qq = tid >> 8;
        float4 bi = sBox[row];
        float  ai = (bi.z-bi.x)*(bi.w-bi.y);
        unsigned long long mv = 0;
#pragma unroll 8
        for (int jj = 0; jj < 64; ++jj) {
            int j = qq*64 + jj;
            float4 bj = sBox[j];
            float aj = (bj.z-bj.x)*(bj.w-bj.y);
            float iw = fmaxf(fminf(bj.z,bi.z)-fmaxf(bj.x,bi.x),0.f);
            float ih = fmaxf(fminf(bj.w,bi.w)-fmaxf(bj.y,bi.y),0.f);
            float in_ = iw*ih;
            bool s = (j > row) && (in_/(aj+ai-in_+1e-12f) > 0.6f);
            mv |= ((unsigned long long)s) << jj;
        }
        sRow[row][qq] = mv;
    }
    __syncthreads();

    // ---- serial bitmask walk (thread 0): ~5cy/suppressed, ~130cy/accept ----
    if (tid == 0) {
        int na = 0;
        unsigned long long r0=0, r1=0, r2=0, r3=0;
#define FCOS_WBLK(RW, IB)                                                  \
        {                                                                  \
            int hi = nValid < ((IB)+1)*64 ? nValid : ((IB)+1)*64;          \
            for (int i = (IB)*64; i < hi && na < 100; ++i) {               \
                if ((RW >> (i - (IB)*64)) & 1ull) continue;                \
                accIdx[na++] = i;                                          \
                const ulonglong2* rp = (const ulonglong2*)sRow[i];         \
                ulonglong2 ra = rp[0], rb = rp[1];                         \
                r0 |= ra.x; r1 |= ra.y; r2 |= rb.x; r3 |= rb.y;            \
            }                                                              \
        }
        FCOS_WBLK(r0,0) FCOS_WBLK(r1,1) FCOS_WBLK(r2,2) FCOS_WBLK(r3,3)
#undef FCOS_WBLK
        shNaM = na; shNa = na;
    }
    __syncthreads();

    // ---- fallback: top-256 exhausted before 100 accepted (never on real ----
    // data; guarded by nValid==256 since keys below rank 256 have score <=
    // sorted[255]'s). Full-block scan over all positions per step.
    int naM = shNaM;
    if (naM < 100 && nValid == 256) {
        if (tid < naM) accBox[tid] = sBox[accIdx[tid]];
        if (tid == 0) shLast = sorted[255];
        __syncthreads();
        while (true) {
            if (shNa >= 100) break;
            unsigned long long last = shLast;
            unsigned long long bk = 0;
            for (int i = tid; i < NPOS; i += BT) {
                unsigned long long k2 = mkkey(gs[i], i);
                if (k2 < last && k2 > bk) bk = k2;
            }
#pragma unroll
            for (int off = 32; off > 0; off >>= 1) {
                unsigned long long o = __shfl_down(bk, off);
                if (o > bk) bk = o;
            }
            int lane = tid & 63, wv = tid >> 6;
            if (lane == 0) eqKey[wv] = bk;
            __syncthreads();
            if (tid == 0) {
                unsigned long long best = 0;
                for (int q = 0; q < NW; ++q) if (eqKey[q] > best) best = eqKey[q];
                shLast = best;
            }
            __syncthreads();
            unsigned long long ck = shLast;
            if (ck == 0ULL) break;
            float sc = __uint_as_float((unsigned int)(ck >> 16));
            if (!(sc > MINS)) break;
            int p = 65535 - (int)(ck & 0xFFFF);
            float4 bb = computeBox(P, img, p);
            float ba = (bb.z-bb.x)*(bb.w-bb.y);
            int na = shNa;
            bool mySup = false;
            if (tid < na) {
                float4 ab = accBox[tid];
                float aa = (ab.z-ab.x)*(ab.w-ab.y);
                float iw = fmaxf(fminf(bb.z,ab.z)-fmaxf(bb.x,ab.x),0.f);
                float ih = fmaxf(fminf(bb.w,ab.w)-fmaxf(bb.y,ab.y),0.f);
                float in_ = iw*ih;
                mySup = in_/(ba+aa-in_+1e-12f) > 0.6f;
            }
            int supCnt = __syncthreads_count(mySup);
            if (supCnt == 0) {
                if (tid == 0) {
                    int na2 = shNa;
                    outS[na2] = sc;
                    outC[na2] = (float)gCls[p];
                    outB[4*na2+0]=bb.x; outB[4*na2+1]=bb.y;
                    outB[4*na2+2]=bb.z; outB[4*na2+3]=bb.w;
                    accBox[na2] = bb;
                    shNa = na2 + 1;
                }
            }
            __syncthreads();
        }
    }
    __syncthreads();

    // ---- parallel epilogue: main accepts from LDS; -1 fill for the rest ----
    {
        int naM2 = shNaM, naT = shNa;
        if (tid < 100) {
            if (tid < naM2) {
                int r = accIdx[tid];
                unsigned long long k = sorted[r];
                float4 b = sBox[r];
                outS[tid] = __uint_as_float((unsigned int)(k >> 16));
                outC[tid] = sCls[r];
                outB[4*tid+0]=b.x; outB[4*tid+1]=b.y;
                outB[4*tid+2]=b.z; outB[4*tid+3]=b.w;
            } else if (tid >= naT) {     // (naM..naT) written by fallback
                outS[tid] = -1.f; outC[tid] = -1.f;
                outB[4*tid+0]=-1.f; outB[4*tid+1]=-1.f;
                outB[4*tid+2]=-1.f; outB[4*tid+3]=-1.f;
            }
        }
    }
}

extern "C" void kernel_launch(void* const* d_in, const int* in_sizes, int n_in,
                              void* d_out, int out_size, void* d_ws, size_t ws_size,
                              hipStream_t stream) {
    Ptrs P;
    bool interleaved = (in_sizes[1] == 8 * 128 * 128 * 4);
    for (int i = 0; i < 5; ++i) {
        if (interleaved) {
            P.cls[i] = (const float*)d_in[3*i];
            P.reg[i] = (const float*)d_in[3*i + 1];
            P.ctr[i] = (const float*)d_in[3*i + 2];
        } else {
            P.cls[i] = (const float*)d_in[i];
            P.reg[i] = (const float*)d_in[5 + i];
            P.ctr[i] = (const float*)d_in[10 + i];
        }
    }

    char* wbase = (char*)d_ws;
    size_t off = 0;
    auto alloc = [&](size_t bytes) -> void* {
        void* r = wbase + off;
        off += (bytes + 255) & ~(size_t)255;
        return r;
    };
    float*              scoreAll = (float*)alloc((size_t)8 * NPOS * 4);
    int*                clsAll   = (int*)alloc((size_t)8 * NPOS * 4);
    unsigned long long* list     = (unsigned long long*)alloc((size_t)8 * CAP * 8);
    int*                listCnt  = (int*)alloc((size_t)8 * 4);

    hipMemsetAsync(listCnt, 0, 8 * sizeof(int), stream);

    dim3 gA(341, 8);   // 341*64 = 21824 positions, level boundaries block-aligned
    k_score <<<gA, 256, 0, stream>>>(P, scoreAll, clsAll, list, listCnt);
    k_nms   <<<8, BT, 0, stream>>>(P, scoreAll, clsAll, list, listCnt, (float*)d_out);
}

// Round 5
// 153.972 us; speedup vs baseline: 1.5665x; 1.5665x over previous
//
#include <hip/hip_runtime.h>

#define NPOS 21824          // 16384+4096+1024+256+64 positions per image
#define MINS 0.05f
#define BT   1024           // threads per block for k_nms (16 waves)
#define NW   (BT/64)
#define TFAST 0.85f         // static pre-filter threshold (fast path only)
#define CAP  16384          // per-image compact-list capacity
#define CNTSTRIDE 32        // listCnt padding: 32 ints = 128 B (no false sharing)

struct Ptrs { const float* cls[5]; const float* reg[5]; const float* ctr[5]; };

__device__ __forceinline__ float sigf(float x){ return 1.0f/(1.0f+expf(-x)); }

// key = (score_bits<<16) | (65535-p): desc key == desc score, ties lower p.
// Matches reference ordering (concatenation order = level-major position p;
// argmax picks first max; jax top_k keeps lower index on ties).
__device__ __forceinline__ unsigned long long mkkey(unsigned int b, int p){
    return ((unsigned long long)b << 16) | (unsigned)(65535 - p);
}

// Recompute the snapped box for position p (bit-identical to the original
// k_score path: same expression order, same expf, same casts/clamps).
__device__ __forceinline__ float4 computeBox(const Ptrs& P, int img, int p){
    int base, lw, stride, lvl;
    if (p < 16384)      { lvl=0; base=0;     lw=7; stride=8;   }
    else if (p < 20480) { lvl=1; base=16384; lw=6; stride=16;  }
    else if (p < 21504) { lvl=2; base=20480; lw=5; stride=32;  }
    else if (p < 21760) { lvl=3; base=21504; lw=4; stride=64;  }
    else                { lvl=4; base=21760; lw=3; stride=128; }
    int pl = p - base;
    int h = pl >> lw, w = pl & ((1<<lw)-1);
    long long lidx = (long long)img*(1<<(2*lw)) + pl;
    float4 rg = ((const float4*)P.reg[lvl])[lidx];
    float x = (w + 0.5f)*(float)stride;
    float y = (h + 0.5f)*(float)stride;
    int ix1 = (int)(x - expf(rg.x));
    int iy1 = (int)(y - expf(rg.y));
    int ix2 = (int)(x + expf(rg.z));
    int iy2 = (int)(y + expf(rg.w));
    ix1 = max(ix1,0); iy1 = max(iy1,0);
    ix2 = min(ix2,1023); iy2 = min(iy2,1023);
    return make_float4((float)ix1,(float)iy1,(float)ix2,(float)iy2);
}

// ---------------- Kernel A: score / class + compact candidate list ---------
// List append is block-aggregated: LDS ticket + ONE global atomic per block
// (341 per image, spread over 128-B-padded counters) instead of per-thread
// atomics hammering a single cacheline (the round-4 regression).
__global__ __launch_bounds__(256) void k_score(Ptrs P, float* scoreAll, int* clsAll,
                                               unsigned long long* list, int* listCnt)
{
    __shared__ int lcnt, lbase;
    int img  = blockIdx.y;
    int blk  = blockIdx.x;           // [0,341)
    int tid  = threadIdx.x;
    int posb = tid >> 2;             // position within block [0,64)
    int l    = tid & 3;              // lane within 4-lane group
    int p    = blk*64 + posb;
    int lvl, base, lw;
    if (blk < 256)      { lvl=0; base=0;     lw=7; }
    else if (blk < 320) { lvl=1; base=16384; lw=6; }
    else if (blk < 336) { lvl=2; base=20480; lw=5; }
    else if (blk < 340) { lvl=3; base=21504; lw=4; }
    else                { lvl=4; base=21760; lw=3; }
    int pl = p - base;
    long long lidx = (long long)img*(1<<(2*lw)) + pl;

    if (tid == 0) lcnt = 0;
    __syncthreads();

    const float4* c4 = (const float4*)(P.cls[lvl] + lidx*80);
    float mx = -3.4e38f; int mi = 0;
#pragma unroll
    for (int j = 0; j < 5; ++j) {
        int k = j*4 + l;
        float4 v = c4[k];
        int cb = k*4;
        if (v.x > mx){mx=v.x; mi=cb;}
        if (v.y > mx){mx=v.y; mi=cb+1;}
        if (v.z > mx){mx=v.z; mi=cb+2;}
        if (v.w > mx){mx=v.w; mi=cb+3;}
    }
#pragma unroll
    for (int d = 1; d < 4; d <<= 1) {
        float omx = __shfl_xor(mx, d);
        int   omi = __shfl_xor(mi, d);
        if (omx > mx || (omx == mx && omi < mi)) { mx = omx; mi = omi; }
    }
    int myTicket = -1;
    unsigned long long myKey = 0;
    if (l == 0) {
        float ct = P.ctr[lvl][lidx];
        float sc = sqrtf(sigf(mx)*sigf(ct));   // sigmoid(max)==max(sigmoid)
        int o = img*NPOS + p;
        scoreAll[o] = sc;
        clsAll[o]   = mi;
        if (sc > TFAST) {                      // LDS ticket (cheap)
            myTicket = atomicAdd(&lcnt, 1);
            myKey = mkkey(__float_as_uint(sc), p);
        }
    }
    __syncthreads();
    if (tid == 0) lbase = lcnt ? atomicAdd(&listCnt[img*CNTSTRIDE], lcnt) : 0;
    __syncthreads();
    if (myTicket >= 0) {
        int t = lbase + myTicket;
        if (t < CAP) list[(long long)img*CAP + t] = myKey;
    }
}

// ---- suffix-scan pick over a 2048-bin LDS histogram (2 bins/thread) --------
// Finds the bin where the descending cumulative count crosses K; writes
// shPref = prefBase | (bin<<shift), shK = K remaining within that bin.
__device__ void suffix_pick(const int* hist, int* wsum, int K,
                            unsigned int prefBase, int shift,
                            unsigned int* shPref, int* shK, int tid)
{
    int lo = tid*2;
    int h0 = hist[lo], h1 = hist[lo+1];
    int ls = h0 + h1;
    int lane = tid & 63, wv = tid >> 6;
    int v = ls;
#pragma unroll
    for (int off = 1; off < 64; off <<= 1) {
        int o = __shfl_down(v, off);
        if (lane + off < 64) v += o;
    }
    if (lane == 0) wsum[wv] = v;
    __syncthreads();
    int add = 0;
    for (int q = wv + 1; q < NW; ++q) add += wsum[q];
    int mine = v + add;              // count in bins [lo..2047]
    int above = mine - ls;           // count in bins [lo+2..2047]
    if (above < K && mine >= K) {    // exactly one thread crosses
        if (above + h1 >= K) { *shPref = prefBase | ((unsigned)(lo+1) << shift); *shK = K - above; }
        else                 { *shPref = prefBase | ((unsigned)lo << shift); *shK = K - above - h1; }
    }
    __syncthreads();
}

// ------ Kernel B: global top-256 + rank + matrix-NMS (8 blocks, 1024 thr) ---
// Fast path: radix-select over the compact list (all positions with
// score > TFAST). cnt>=256 guarantees the global top-256 is inside the list
// (256th score > TFAST); cnt<=CAP guarantees no append was dropped. Otherwise
// fall back to exact full-scan radix over scoreAll.
// Greedy NMS == sequential scan over rank order with a 256-bit suppression
// mask: candidate i accepted iff bit i clear; on accept, OR in row i of the
// precomputed (parallel-built) IoU>thr matrix. Identical decisions to serial
// greedy NMS.
__global__ __launch_bounds__(BT) void k_nms(Ptrs P, const float* scoreAll,
                                            const int* clsAll,
                                            const unsigned long long* list,
                                            const int* listCnt, float* out)
{
    __shared__ int histA[2048], histB[2048], wsum[NW];
    __shared__ unsigned int shPref;
    __shared__ int shK, tick, eqn;
    __shared__ unsigned long long eqKey[1024];
    __shared__ unsigned long long sel[256];
    __shared__ unsigned long long sorted[256];
    __shared__ float4 sBox[256];
    __shared__ float  sCls[256];
    __shared__ __align__(16) unsigned long long sRow[256][4];
    __shared__ int accIdx[100];
    __shared__ float4 accBox[100];
    __shared__ int shNaM, shNa;
    __shared__ unsigned long long shLast;

    int img = blockIdx.x, tid = threadIdx.x;
    const unsigned int* gs = (const unsigned int*)scoreAll + (long long)img*NPOS;
    const int* gCls = clsAll + (long long)img*NPOS;
    const unsigned long long* gl = list + (long long)img*CAP;

    float* outS = out + img*100;
    float* outC = out + 800 + img*100;
    float* outB = out + 1600 + img*400;

    int cnt = listCnt[img*CNTSTRIDE];
    bool fastPath = (cnt >= 256 && cnt <= CAP);

    for (int i = tid; i < 2048; i += BT) { histA[i] = 0; histB[i] = 0; }
    if (tid == 0) { tick = 0; eqn = 0; }
    __syncthreads();

    unsigned int kth; int need;
    if (fastPath) {
        // ---- radix over compact list (key>>35 = score_bits>>19) ----
        for (int i = tid; i < cnt; i += BT)
            atomicAdd(&histA[(unsigned)(gl[i] >> 35)], 1);
        __syncthreads();
        suffix_pick(histA, wsum, 256, 0u, 19, &shPref, &shK, tid);
        unsigned int pref = shPref; int K2 = shK;
        for (int i = tid; i < cnt; i += BT) {
            unsigned long long k = gl[i];
            if ((unsigned)(k >> 35) == (pref >> 19))
                atomicAdd(&histB[(unsigned)(k >> 24) & 2047], 1);
        }
        __syncthreads();
        suffix_pick(histB, wsum, K2, pref, 8, &shPref, &shK, tid);
        kth = shPref >> 8; need = shK;
        for (int i = tid; i < cnt; i += BT) {
            unsigned long long k = gl[i];
            unsigned int hb = (unsigned)(k >> 24);
            if (hb > kth)       { int t = atomicAdd(&tick, 1); sel[t] = k; }
            else if (hb == kth) { int t = atomicAdd(&eqn, 1); if (t < 1024) eqKey[t] = k; }
        }
    } else {
        // ---- exact full-scan radix over all positions ----
#pragma unroll 4
        for (int i = tid; i < NPOS; i += BT)
            atomicAdd(&histA[gs[i] >> 19], 1);
        __syncthreads();
        suffix_pick(histA, wsum, 256, 0u, 19, &shPref, &shK, tid);
        unsigned int pref = shPref; int K2 = shK;
#pragma unroll 4
        for (int i = tid; i < NPOS; i += BT) {
            unsigned int b = gs[i];
            if ((b >> 19) == (pref >> 19)) atomicAdd(&histB[(b >> 8) & 2047], 1);
        }
        __syncthreads();
        suffix_pick(histB, wsum, K2, pref, 8, &shPref, &shK, tid);
        kth = shPref >> 8; need = shK;
#pragma unroll 4
        for (int i = tid; i < NPOS; i += BT) {
            unsigned int b = gs[i], hb = b >> 8;
            if (hb > kth)       { int t = atomicAdd(&tick, 1); sel[t] = mkkey(b, i); }
            else if (hb == kth) { int t = atomicAdd(&eqn, 1); if (t < 1024) eqKey[t] = mkkey(b, i); }
        }
    }
    __syncthreads();
    int m = eqn, nG = tick;              // nG == 256-need
    if (m <= 1024) {                     // keep `need` LARGEST keys among ties
        for (int q = tid; q < m; q += BT) {
            unsigned long long kq = eqKey[q];
            int r = 0;
            for (int j = 0; j < m; ++j) r += (eqKey[j] > kq);
            if (r < need) sel[nG + r] = kq;
        }
    } else if (tid == 0) {               // unreachable-in-practice fallback
        unsigned long long last = ~0ULL;
        for (int c = 0; c < need; ++c) {
            unsigned long long best = 0;
            if (fastPath) {
                for (int i = 0; i < cnt; ++i) {
                    unsigned long long k2 = gl[i];
                    if ((unsigned)(k2 >> 24) == kth && k2 < last && k2 > best) best = k2;
                }
            } else {
                for (int i = 0; i < NPOS; ++i) {
                    unsigned int b = gs[i];
                    if ((b >> 8) == kth) {
                        unsigned long long k2 = mkkey(b, i);
                        if (k2 < last && k2 > best) best = k2;
                    }
                }
            }
            sel[nG + c] = best; last = best;
        }
    }
    __syncthreads();

    // rank 256 unique keys by counting (1 key/thread, broadcast LDS reads)
    if (tid < 256) {
        unsigned long long k = sel[tid];
        int r = 0;
        for (int j = 0; j < 256; ++j) r += (sel[j] > k);
        sorted[r] = k;
    }
    __syncthreads();
    if (tid < 256) {
        int p = 65535 - (int)(sorted[tid] & 0xFFFF);
        sBox[tid] = computeBox(P, img, p);
        sCls[tid] = (float)gCls[p];
    }

    // nValid = # leading candidates with score > MINS (sorted desc, so prefix).
    // __syncthreads_count doubles as the barrier covering sBox/sCls writes.
    float myScore = 0.f;
    if (tid < 256) myScore = __uint_as_float((unsigned int)(sorted[tid] >> 16));
    int nValid = __syncthreads_count(myScore > MINS ? 1 : 0);

    // ---- suppression matrix: thread (row,quarter) builds 64 bits of row ----
    // Float arithmetic order matches serial greedy NMS exactly:
    // den = area(candidate j) + area(accepted i) - inter + 1e-12.
    {
        int row = tid & 255, qq = tid >> 8;
        float4 bi = sBox[row];
        float  ai = (bi.z-bi.x)*(bi.w-bi.y);
        unsigned long long mv = 0;
#pragma unroll 8
        for (int jj = 0; jj < 64; ++jj) {
            int j = qq*64 + jj;
            float4 bj = sBox[j];
            float aj = (bj.z-bj.x)*(bj.w-bj.y);
            float iw = fmaxf(fminf(bj.z,bi.z)-fmaxf(bj.x,bi.x),0.f);
            float ih = fmaxf(fminf(bj.w,bi.w)-fmaxf(bj.y,bi.y),0.f);
            float in_ = iw*ih;
            bool s = (j > row) && (in_/(aj+ai-in_+1e-12f) > 0.6f);
            mv |= ((unsigned long long)s) << jj;
        }
        sRow[row][qq] = mv;
    }
    __syncthreads();

    // ---- serial bitmask walk (thread 0): ~5cy/suppressed, ~130cy/accept ----
    if (tid == 0) {
        int na = 0;
        unsigned long long r0=0, r1=0, r2=0, r3=0;
#define FCOS_WBLK(RW, IB)                                                  \
        {                                                                  \
            int hi = nValid < ((IB)+1)*64 ? nValid : ((IB)+1)*64;          \
            for (int i = (IB)*64; i < hi && na < 100; ++i) {               \
                if ((RW >> (i - (IB)*64)) & 1ull) continue;                \
                accIdx[na++] = i;                                          \
                const ulonglong2* rp = (const ulonglong2*)sRow[i];         \
                ulonglong2 ra = rp[0], rb = rp[1];                         \
                r0 |= ra.x; r1 |= ra.y; r2 |= rb.x; r3 |= rb.y;            \
            }                                                              \
        }
        FCOS_WBLK(r0,0) FCOS_WBLK(r1,1) FCOS_WBLK(r2,2) FCOS_WBLK(r3,3)
#undef FCOS_WBLK
        shNaM = na; shNa = na;
    }
    __syncthreads();

    // ---- fallback: top-256 exhausted before 100 accepted (never on real ----
    // data; guarded by nValid==256 since keys below rank 256 have score <=
    // sorted[255]'s). Full-block scan over all positions per step.
    int naM = shNaM;
    if (naM < 100 && nValid == 256) {
        if (tid < naM) accBox[tid] = sBox[accIdx[tid]];
        if (tid == 0) shLast = sorted[255];
        __syncthreads();
        while (true) {
            if (shNa >= 100) break;
            unsigned long long last = shLast;
            unsigned long long bk = 0;
            for (int i = tid; i < NPOS; i += BT) {
                unsigned long long k2 = mkkey(gs[i], i);
                if (k2 < last && k2 > bk) bk = k2;
            }
#pragma unroll
            for (int off = 32; off > 0; off >>= 1) {
                unsigned long long o = __shfl_down(bk, off);
                if (o > bk) bk = o;
            }
            int lane = tid & 63, wv = tid >> 6;
            if (lane == 0) eqKey[wv] = bk;
            __syncthreads();
            if (tid == 0) {
                unsigned long long best = 0;
                for (int q = 0; q < NW; ++q) if (eqKey[q] > best) best = eqKey[q];
                shLast = best;
            }
            __syncthreads();
            unsigned long long ck = shLast;
            if (ck == 0ULL) break;
            float sc = __uint_as_float((unsigned int)(ck >> 16));
            if (!(sc > MINS)) break;
            int p = 65535 - (int)(ck & 0xFFFF);
            float4 bb = computeBox(P, img, p);
            float ba = (bb.z-bb.x)*(bb.w-bb.y);
            int na = shNa;
            bool mySup = false;
            if (tid < na) {
                float4 ab = accBox[tid];
                float aa = (ab.z-ab.x)*(ab.w-ab.y);
                float iw = fmaxf(fminf(bb.z,ab.z)-fmaxf(bb.x,ab.x),0.f);
                float ih = fmaxf(fminf(bb.w,ab.w)-fmaxf(bb.y,ab.y),0.f);
                float in_ = iw*ih;
                mySup = in_/(ba+aa-in_+1e-12f) > 0.6f;
            }
            int supCnt = __syncthreads_count(mySup);
            if (supCnt == 0) {
                if (tid == 0) {
                    int na2 = shNa;
                    outS[na2] = sc;
                    outC[na2] = (float)gCls[p];
                    outB[4*na2+0]=bb.x; outB[4*na2+1]=bb.y;
                    outB[4*na2+2]=bb.z; outB[4*na2+3]=bb.w;
                    accBox[na2] = bb;
                    shNa = na2 + 1;
                }
            }
            __syncthreads();
        }
    }
    __syncthreads();

    // ---- parallel epilogue: main accepts from LDS; -1 fill for the rest ----
    {
        int naM2 = shNaM, naT = shNa;
        if (tid < 100) {
            if (tid < naM2) {
                int r = accIdx[tid];
                unsigned long long k = sorted[r];
                float4 b = sBox[r];
                outS[tid] = __uint_as_float((unsigned int)(k >> 16));
                outC[tid] = sCls[r];
                outB[4*tid+0]=b.x; outB[4*tid+1]=b.y;
                outB[4*tid+2]=b.z; outB[4*tid+3]=b.w;
            } else if (tid >= naT) {     // (naM..naT) written by fallback
                outS[tid] = -1.f; outC[tid] = -1.f;
                outB[4*tid+0]=-1.f; outB[4*tid+1]=-1.f;
                outB[4*tid+2]=-1.f; outB[4*tid+3]=-1.f;
            }
        }
    }
}

extern "C" void kernel_launch(void* const* d_in, const int* in_sizes, int n_in,
                              void* d_out, int out_size, void* d_ws, size_t ws_size,
                              hipStream_t stream) {
    Ptrs P;
    bool interleaved = (in_sizes[1] == 8 * 128 * 128 * 4);
    for (int i = 0; i < 5; ++i) {
        if (interleaved) {
            P.cls[i] = (const float*)d_in[3*i];
            P.reg[i] = (const float*)d_in[3*i + 1];
            P.ctr[i] = (const float*)d_in[3*i + 2];
        } else {
            P.cls[i] = (const float*)d_in[i];
            P.reg[i] = (const float*)d_in[5 + i];
            P.ctr[i] = (const float*)d_in[10 + i];
        }
    }

    char* wbase = (char*)d_ws;
    size_t off = 0;
    auto alloc = [&](size_t bytes) -> void* {
        void* r = wbase + off;
        off += (bytes + 255) & ~(size_t)255;
        return r;
    };
    float*              scoreAll = (float*)alloc((size_t)8 * NPOS * 4);
    int*                clsAll   = (int*)alloc((size_t)8 * NPOS * 4);
    unsigned long long* list     = (unsigned long long*)alloc((size_t)8 * CAP * 8);
    int*                listCnt  = (int*)alloc((size_t)8 * CNTSTRIDE * 4);

    hipMemsetAsync(listCnt, 0, 8 * CNTSTRIDE * sizeof(int), stream);

    dim3 gA(341, 8);   // 341*64 = 21824 positions, level boundaries block-aligned
    k_score <<<gA, 256, 0, stream>>>(P, scoreAll, clsAll, list, listCnt);
    k_nms   <<<8, BT, 0, stream>>>(P, scoreAll, clsAll, list, listCnt, (float*)d_out);
}